// Round 7
// baseline (295.165 us; speedup 1.0000x reference)
//
#include <hip/hip_runtime.h>

typedef unsigned short u16;
typedef unsigned int   u32;

#define IM_H    240
#define IM_W    320
#define ENV_COL 160
#define NPIX    19200           // ENV_ROW*ENV_COL
#define NGRIDS  384
#define BATCH   2

#define ACC_SIZE (BATCH*3*NGRIDS*NPIX)      // 44,236,800
#define MASK_OFF ACC_SIZE
#define MEAN_OFF (ACC_SIZE + BATCH*NPIX)

// workspace layout (floats). Every slot written exactly once by k_main
// (plain stores, no atomics) -> NO memset needed.
#define WS_WPART   0                        // [B*600 blocks][2 halves][1152]
#define WPART_N    (BATCH*600*2*1152)       // 2,764,800 floats (11.06 MB)
#define WS_MPART   WPART_N                  // [B*600][2] mask half-sums

#define PI_F  3.14159265358979f
#define PI_2F 1.57079632679490f

__device__ __forceinline__ u16 f2bf(float f) {
    u32 x = __float_as_uint(f);
    x += 0x7fffu + ((x >> 16) & 1u);        // RNE
    return (u16)(x >> 16);
}

// 16-lane (DPP row) sum: 4 x v_add_f32_dpp row_ror — pure VALU, no LDS pipe.
// (proven R4/R6: identical absmax)
__device__ __forceinline__ float row16_sum(float v) {
    v += __int_as_float(__builtin_amdgcn_update_dpp(
             0, __float_as_int(v), 0x128, 0xf, 0xf, false));   // row_ror:8
    v += __int_as_float(__builtin_amdgcn_update_dpp(
             0, __float_as_int(v), 0x124, 0xf, 0xf, false));   // row_ror:4
    v += __int_as_float(__builtin_amdgcn_update_dpp(
             0, __float_as_int(v), 0x122, 0xf, 0xf, false));   // row_ror:2
    v += __int_as_float(__builtin_amdgcn_update_dpp(
             0, __float_as_int(v), 0x121, 0xf, 0xf, false));   // row_ror:1
    return v;
}

// acos via sqrt(1-|x|)*poly, max err ~6.8e-5 rad (A&S 4.4.45)
__device__ __forceinline__ float fast_acos(float x) {
    float ax = fabsf(x);
    float s  = sqrtf(fmaxf(1.0f - ax, 0.0f));
    float p  = ((-0.0187293f * ax + 0.0742610f) * ax - 0.2121144f) * ax + 1.5707288f;
    float r  = s * p;
    return (x < 0.0f) ? (PI_F - r) : r;
}

// full-quadrant atan2, Hastings deg-9 minimax on [0,1], err ~1e-5 rad
__device__ __forceinline__ float fast_atan2(float y, float x) {
    float ax = fabsf(x), ay = fabsf(y);
    float mx = fmaxf(ax, ay), mn = fminf(ax, ay);
    float t  = mn * __builtin_amdgcn_rcpf(fmaxf(mx, 1e-37f));
    float t2 = t * t;
    float p  = ((((0.0208351f * t2 - 0.0851330f) * t2 + 0.1801410f) * t2
                 - 0.3302995f) * t2 + 0.9998660f) * t;
    p = (ay > ax) ? (PI_2F - p) : p;
    p = (x < 0.0f) ? (PI_F - p) : p;
    return __builtin_copysignf(p, y);
}

// ---------------------------------------------------------------- main kernel
// R5-exact LDS footprint (32,384 B -> 5 blocks/CU, grid 1200 fully resident,
// no tail) + fused sums: per-iter DPP row sums stored DIRECTLY to global
// wpart with plain stores (each (bid,half,n,ch) written exactly once — no
// atomics, no LDS psum, no flush loop, no memset).
__global__ __launch_bounds__(256, 4) void k_main(
        const float* __restrict__ normal,
        const float* __restrict__ depth,
        const float* __restrict__ envm,
        const float* __restrict__ camK,
        const float* __restrict__ camR,
        const float* __restrict__ layout,
        float* __restrict__ wpart,
        float* __restrict__ mpart,
        float* __restrict__ out) {

    __shared__ __align__(16) u32   env01[128 * 32];   // (ch1<<16)|ch0, [texel][pix]
    __shared__               u16   env2 [128 * 32];   // ch2 bf16, [texel][pix]
    __shared__ __align__(16) float cen_s[NGRIDS * 4]; // float4-padded centers
    __shared__               float pgeo[32][13];      // pt(3) Ainv(9) mask(1)

    const int tid = threadIdx.x;
    const int bid = blockIdx.x;
    const int b   = bid / 600;
    const int pg  = bid % 600;       // 0..599 pixel group (32 px)
    const int p0  = pg * 32;

    // ---- centers for all 384 grids
    {
        const int B0[6] = {3, 7, 4, 6, 7, 7};
        const int B1[6] = {2, 6, 5, 2, 6, 3};
        const int B2[6] = {0, 4, 0, 5, 3, 4};
        for (int idx = tid; idx < NGRIDS; idx += 256) {
            int f = idx >> 6, gi = (idx >> 3) & 7, hj = idx & 7;
            int t0 = B0[f], t1 = B1[f], t2 = B2[f];
            float cw[3];
            #pragma unroll
            for (int j = 0; j < 3; ++j) {
                float o  = layout[(b * 8 + t0) * 3 + j];
                float e1 = (layout[(b * 8 + t1) * 3 + j] - o) * 0.125f;
                float e2 = (layout[(b * 8 + t2) * 3 + j] - o) * 0.125f;
                cw[j] = e1 * ((float)gi + 0.5f) + e2 * ((float)hj + 0.5f) + o;
            }
            // v = R^T * cw, then M12^T: (v_z, v_y, -v_x)
            float v0 = camR[b*9+0]*cw[0] + camR[b*9+3]*cw[1] + camR[b*9+6]*cw[2];
            float v1 = camR[b*9+1]*cw[0] + camR[b*9+4]*cw[1] + camR[b*9+7]*cw[2];
            float v2 = camR[b*9+2]*cw[0] + camR[b*9+5]*cw[1] + camR[b*9+8]*cw[2];
            cen_s[idx * 4 + 0] = v2;
            cen_s[idx * 4 + 1] = v1;
            cen_s[idx * 4 + 2] = -v0;
            cen_s[idx * 4 + 3] = 0.0f;
        }
    }

    // ---- stage env tile once (f32 -> packed bf16 LDS). 1024 tasks =
    // 32 pix x 32 texel-quads; lanes = consecutive pixels -> LDS write
    // bank = pix (2-way across wave halves = free).
    #pragma unroll
    for (int k = 0; k < 4; ++k) {
        int ci  = tid + k * 256;          // 0..1023
        int pix = ci & 31;
        int tq  = ci >> 5;                // 0..31
        size_t base = ((size_t)b * 3 * NPIX + p0 + pix) * 128 + tq * 4;
        const float4 v0 = *reinterpret_cast<const float4*>(&envm[base]);
        const float4 v1 = *reinterpret_cast<const float4*>(&envm[base + (size_t)NPIX * 128]);
        const float4 v2 = *reinterpret_cast<const float4*>(&envm[base + (size_t)2 * NPIX * 128]);
        const float a0[4] = {v0.x, v0.y, v0.z, v0.w};
        const float a1[4] = {v1.x, v1.y, v1.z, v1.w};
        const float a2[4] = {v2.x, v2.y, v2.z, v2.w};
        #pragma unroll
        for (int j = 0; j < 4; ++j) {
            int t = tq * 4 + j;
            env01[t * 32 + pix] = ((u32)f2bf(a1[j]) << 16) | (u32)f2bf(a0[j]);
            env2 [t * 32 + pix] = f2bf(a2[j]);
        }
    }

    // ---- per-pixel geometry (32 threads) + mask output + mask half-sums
    if (tid < 32) {
        int p = p0 + tid;
        int r = p / ENV_COL, c = p % ENV_COL;
        float nv[3];
        #pragma unroll
        for (int ch = 0; ch < 3; ++ch) {
            const float* np_ = &normal[((size_t)(b * 3 + ch) * IM_H + 2 * r) * IM_W + 2 * c];
            nv[ch] = 0.25f * (np_[0] + np_[1] + np_[IM_W] + np_[IM_W + 1]);
        }
        float s2 = nv[0]*nv[0] + nv[1]*nv[1] + nv[2]*nv[2];
        s2 = fminf(fmaxf(s2, 1e-6f), 1.0f);
        float inv = 1.0f / sqrtf(s2);
        nv[0] *= inv; nv[1] *= inv; nv[2] *= inv;
        // camy = normalize(up - (up.n) n), up=(0,1,0)
        float ty0 = -nv[1]*nv[0], ty1 = 1.0f - nv[1]*nv[1], ty2 = -nv[1]*nv[2];
        float tn = fmaxf(sqrtf(ty0*ty0 + ty1*ty1 + ty2*ty2), 1e-12f);
        float cy0 = ty0/tn, cy1 = ty1/tn, cy2 = ty2/tn;
        // camx = -normalize(cross(camy, n))
        float cr0 = cy1*nv[2] - cy2*nv[1];
        float cr1 = cy2*nv[0] - cy0*nv[2];
        float cr2 = cy0*nv[1] - cy1*nv[0];
        float cnm = fmaxf(sqrtf(cr0*cr0 + cr1*cr1 + cr2*cr2), 1e-12f);
        float cx0 = -cr0/cnm, cx1 = -cr1/cnm, cx2 = -cr2/cnm;
        // A = [camx camy n] columns, + 1e-6 I ; invert (adjugate)
        float a = cx0 + 1e-6f, bb = cy0,         cc = nv[0];
        float d = cx1,         e  = cy1 + 1e-6f, f  = nv[1];
        float g2 = cx2,        h  = cy2,         i  = nv[2] + 1e-6f;
        float c00 = e*i - f*h,   c01 = f*g2 - d*i,  c02 = d*h - e*g2;
        float c10 = cc*h - bb*i, c11 = a*i - cc*g2, c12 = bb*g2 - a*h;
        float c20 = bb*f - cc*e, c21 = cc*d - a*f,  c22 = a*e - bb*d;
        float rdet = 1.0f / (a*c00 + bb*c01 + cc*c02);
        float K00 = camK[b * 9 + 0];
        float K02 = camK[b * 9 + 2];
        float fpix = K00 * (IM_W / 2.0f) / K02;
        float z = -depth[((size_t)b * IM_H + 2 * r) * IM_W + 2 * c];
        float px = -((2.0f * c) - IM_W / 2.0f) / fpix * z;
        float py =  ((2.0f * r) - IM_H / 2.0f) / fpix * z;
        float mask = (z < -0.1f) ? 1.0f : 0.0f;
        pgeo[tid][0] = px;  pgeo[tid][1] = py;  pgeo[tid][2] = z;
        pgeo[tid][3] = c00*rdet; pgeo[tid][4]  = c10*rdet; pgeo[tid][5]  = c20*rdet;
        pgeo[tid][6] = c01*rdet; pgeo[tid][7]  = c11*rdet; pgeo[tid][8]  = c21*rdet;
        pgeo[tid][9] = c02*rdet; pgeo[tid][10] = c12*rdet; pgeo[tid][11] = c22*rdet;
        pgeo[tid][12] = mask;
        out[MASK_OFF + (size_t)b * NPIX + p] = mask;
        // mask 16-lane half-sums -> plain stores (written exactly once)
        float ms = row16_sum(mask);
        if ((tid & 15) == 0) mpart[bid * 2 + (tid >> 4)] = ms;
    }

    __syncthreads();

    const int pix  = tid & 31;
    const int slot = tid >> 5;          // 0..7
    const float ptx = pgeo[pix][0], pty = pgeo[pix][1], ptz = pgeo[pix][2];
    const float A0 = pgeo[pix][3], A1 = pgeo[pix][4],  A2 = pgeo[pix][5];
    const float A3 = pgeo[pix][6], A4 = pgeo[pix][7],  A5 = pgeo[pix][8];
    const float A6 = pgeo[pix][9], A7 = pgeo[pix][10], A8 = pgeo[pix][11];
    const float mscale = pgeo[pix][12] * 0.1f;
    // per-lane wpart base: block region + half select (pix<16 -> 0, else 1)
    float* const wbase = &wpart[((size_t)bid * 2 + (pix >> 4)) * 1152];

    #pragma unroll 4
    for (int it = 0; it < 48; ++it) {
        const int n = it * 8 + slot;                   // 0..383
        const float4 cc4 = *reinterpret_cast<const float4*>(&cen_s[n * 4]);
        const float vx = cc4.x - ptx;
        const float vy = cc4.y - pty;
        const float vz = cc4.z - ptz;
        float lx = A0 * vx + A1 * vy + A2 * vz;
        float ly = A3 * vx + A4 * vy + A5 * vz;
        float lz = A6 * vx + A7 * vy + A8 * vz;
        float rn = __builtin_amdgcn_rsqf(lx * lx + ly * ly + lz * lz);
        float ct = fminf(fmaxf(lz * rn, -1.0f), 1.0f);
        float theta = fast_acos(ct);
        float phi = fast_atan2(ly, lx);                // sin_t>0 divides out
        float az = phi * 2.54647908947032537f + 7.5f;  // phi*(8/pi)+7.5
        float el = theta * 5.09295817894065074f - 0.5f;// theta*(16/pi)-0.5
        float x = fminf(fmaxf(az, 0.0f), 15.0f);
        float y = fminf(fmaxf(el, 0.0f), 7.0f);
        float x0f = floorf(x), y0f = floorf(y);
        float wx = x - x0f, wy = y - y0f;
        int ix0 = (int)x0f, iy0 = (int)y0f;
        int ix1 = min(ix0 + 1, 15), iy1 = min(iy0 + 1, 7);
        int t00 = (iy0 << 4) + ix0;       // texel ids
        int t01 = (iy0 << 4) + ix1;
        int t10 = (iy1 << 4) + ix0;
        int t11 = (iy1 << 4) + ix1;
        u32 c00 = env01[(t00 << 5) + pix], c01 = env01[(t01 << 5) + pix];
        u32 c10 = env01[(t10 << 5) + pix], c11 = env01[(t11 << 5) + pix];
        u32 g00 = env2 [(t00 << 5) + pix], g01 = env2 [(t01 << 5) + pix];
        u32 g10 = env2 [(t10 << 5) + pix], g11 = env2 [(t11 << 5) + pix];
        // fold mask*0.1 into the bilinear weights
        float wy1m = wy * mscale, wy0m = mscale - wy1m;
        float w00 = wy0m * (1.0f - wx), w01 = wy0m * wx;
        float w10 = wy1m * (1.0f - wx), w11 = wy1m * wx;
        float v0 = w00 * __uint_as_float(c00 << 16)
                 + w01 * __uint_as_float(c01 << 16)
                 + w10 * __uint_as_float(c10 << 16)
                 + w11 * __uint_as_float(c11 << 16);
        float v1 = w00 * __uint_as_float(c00 & 0xffff0000u)
                 + w01 * __uint_as_float(c01 & 0xffff0000u)
                 + w10 * __uint_as_float(c10 & 0xffff0000u)
                 + w11 * __uint_as_float(c11 & 0xffff0000u);
        float v2 = w00 * __uint_as_float(g00 << 16)
                 + w01 * __uint_as_float(g01 << 16)
                 + w10 * __uint_as_float(g10 << 16)
                 + w11 * __uint_as_float(g11 << 16);

        size_t obase = ((size_t)b * 3 * NGRIDS + n) * NPIX + p0 + pix;
        out[obase]                             = v0;
        out[obase + (size_t)NGRIDS * NPIX]     = v1;
        out[obase + (size_t)2 * NGRIDS * NPIX] = v2;

        // pure-VALU DPP row sums; lanes 0/16/32/48 hold their row's 16-pixel
        // sum -> plain scattered stores (each address written exactly once
        // across the entire grid; L2 write-combines each block's 9.2KB region)
        float s0 = row16_sum(v0);
        float s1 = row16_sum(v1);
        float s2v = row16_sum(v2);
        if ((pix & 15) == 0) {
            float* wp = wbase + n * 3;
            wp[0] = s0;
            wp[1] = s1;
            wp[2] = s2v;
        }
    }
}

// ------------------------------------------------------------- finalize mean
// one block per output (b,n,ch): sum 1200 partials (600 blocks x 2 halves)
// + redundant 1200-value mask sum (mpart is L2-hot, shared by all blocks).
// Adjacent-i blocks share wpart cache lines 16-way.
__global__ __launch_bounds__(256) void k_final(const float* __restrict__ wpart,
                                               const float* __restrict__ mpart,
                                               float* __restrict__ out) {
    const int bid = blockIdx.x;          // 0..2303 == b*1152 + n*3+ch
    const int tid = threadIdx.x;
    const int b   = bid / 1152;
    const int i   = bid % 1152;          // n*3+ch
    float s = 0.0f, ms = 0.0f;
    for (int j = tid; j < 1200; j += 256) {
        s  += wpart[((size_t)b * 1200 + j) * 1152 + i];
        ms += mpart[b * 1200 + j];
    }
    __shared__ float r1[256], r2[256];
    r1[tid] = s; r2[tid] = ms;
    __syncthreads();
    #pragma unroll
    for (int m = 128; m >= 1; m >>= 1) {
        if (tid < m) { r1[tid] += r1[tid + m]; r2[tid] += r2[tid + m]; }
        __syncthreads();
    }
    if (tid == 0)
        out[MEAN_OFF + bid] = r1[0] / (r2[0] + 1e-6f);
}

extern "C" void kernel_launch(void* const* d_in, const int* in_sizes, int n_in,
                              void* d_out, int out_size, void* d_ws, size_t ws_size,
                              hipStream_t stream) {
    const float* normal = (const float*)d_in[0];
    const float* depth  = (const float*)d_in[1];
    const float* envm   = (const float*)d_in[2];
    const float* camK   = (const float*)d_in[3];
    const float* camR   = (const float*)d_in[4];
    const float* layout = (const float*)d_in[5];
    float* out = (float*)d_out;
    float* ws  = (float*)d_ws;

    k_main<<<dim3(BATCH * 600), dim3(256), 0, stream>>>(normal, depth, envm, camK,
                                                        camR, layout,
                                                        ws + WS_WPART, ws + WS_MPART,
                                                        out);
    k_final<<<dim3(BATCH * 1152), dim3(256), 0, stream>>>(ws + WS_WPART,
                                                          ws + WS_MPART, out);
}

// Round 8
// 273.064 us; speedup vs baseline: 1.0809x; 1.0809x over previous
//
#include <hip/hip_runtime.h>

typedef unsigned short u16;
typedef unsigned int   u32;

#define IM_H    240
#define IM_W    320
#define ENV_COL 160
#define NPIX    19200           // ENV_ROW*ENV_COL
#define NGRIDS  384
#define BATCH   2

#define ACC_SIZE (BATCH*3*NGRIDS*NPIX)      // 44,236,800
#define MASK_OFF ACC_SIZE
#define MEAN_OFF (ACC_SIZE + BATCH*NPIX)

#define NREP    8               // wsum replication (atomic contention /8)
// workspace layout (floats)
#define WS_SUM8    0                            // B*NREP*1152 = 18,432
#define WS_MSUM8   (BATCH*NREP*1152)            // B*NREP = 16
#define WS_ZERO_F  (WS_MSUM8 + BATCH*NREP)      // zeroed region end = 18,448
#define WS_CEN     WS_ZERO_F                    // B*NGRIDS*4 = 3,072 (no memset)

#define PI_F  3.14159265358979f
#define PI_2F 1.57079632679490f

__device__ __forceinline__ u16 f2bf(float f) {
    u32 x = __float_as_uint(f);
    x += 0x7fffu + ((x >> 16) & 1u);        // RNE
    return (u16)(x >> 16);
}

// 16-lane (DPP row) sum: 4 x v_add_f32_dpp row_ror — pure VALU, no LDS pipe.
// (proven R4/R6: identical absmax)
__device__ __forceinline__ float row16_sum(float v) {
    v += __int_as_float(__builtin_amdgcn_update_dpp(
             0, __float_as_int(v), 0x128, 0xf, 0xf, false));   // row_ror:8
    v += __int_as_float(__builtin_amdgcn_update_dpp(
             0, __float_as_int(v), 0x124, 0xf, 0xf, false));   // row_ror:4
    v += __int_as_float(__builtin_amdgcn_update_dpp(
             0, __float_as_int(v), 0x122, 0xf, 0xf, false));   // row_ror:2
    v += __int_as_float(__builtin_amdgcn_update_dpp(
             0, __float_as_int(v), 0x121, 0xf, 0xf, false));   // row_ror:1
    return v;
}

// acos via sqrt(1-|x|)*poly, max err ~6.8e-5 rad (A&S 4.4.45)
__device__ __forceinline__ float fast_acos(float x) {
    float ax = fabsf(x);
    float s  = sqrtf(fmaxf(1.0f - ax, 0.0f));
    float p  = ((-0.0187293f * ax + 0.0742610f) * ax - 0.2121144f) * ax + 1.5707288f;
    float r  = s * p;
    return (x < 0.0f) ? (PI_F - r) : r;
}

// full-quadrant atan2, Hastings deg-9 minimax on [0,1], err ~1e-5 rad
__device__ __forceinline__ float fast_atan2(float y, float x) {
    float ax = fabsf(x), ay = fabsf(y);
    float mx = fmaxf(ax, ay), mn = fminf(ax, ay);
    float t  = mn * __builtin_amdgcn_rcpf(fmaxf(mx, 1e-37f));
    float t2 = t * t;
    float p  = ((((0.0208351f * t2 - 0.0851330f) * t2 + 0.1801410f) * t2
                 - 0.3302995f) * t2 + 0.9998660f) * t;
    p = (ay > ax) ? (PI_2F - p) : p;
    p = (x < 0.0f) ? (PI_F - p) : p;
    return __builtin_copysignf(p, y);
}

// ------------------------------------------------------------- centers kernel
// 768 centers -> float4-padded table in workspace (L1/L2-hot, wave-uniform
// reads in k_main).
__global__ __launch_bounds__(256) void k_centers(const float* __restrict__ layout,
                                                 const float* __restrict__ camR,
                                                 float* __restrict__ cen) {
    int t = blockIdx.x * 256 + threadIdx.x;
    if (t >= BATCH * NGRIDS) return;
    int b = t / NGRIDS, n = t % NGRIDS;
    int f = n >> 6, gi = (n >> 3) & 7, hj = n & 7;
    const int B0[6] = {3, 7, 4, 6, 7, 7};
    const int B1[6] = {2, 6, 5, 2, 6, 3};
    const int B2[6] = {0, 4, 0, 5, 3, 4};
    int t0 = B0[f], t1 = B1[f], t2 = B2[f];
    float cw[3];
    #pragma unroll
    for (int j = 0; j < 3; ++j) {
        float o  = layout[(b * 8 + t0) * 3 + j];
        float e1 = (layout[(b * 8 + t1) * 3 + j] - o) * 0.125f;
        float e2 = (layout[(b * 8 + t2) * 3 + j] - o) * 0.125f;
        cw[j] = e1 * ((float)gi + 0.5f) + e2 * ((float)hj + 0.5f) + o;
    }
    // v = R^T * cw, then M12^T: (v_z, v_y, -v_x)
    float v0 = camR[b*9+0]*cw[0] + camR[b*9+3]*cw[1] + camR[b*9+6]*cw[2];
    float v1 = camR[b*9+1]*cw[0] + camR[b*9+4]*cw[1] + camR[b*9+7]*cw[2];
    float v2 = camR[b*9+2]*cw[0] + camR[b*9+5]*cw[1] + camR[b*9+8]*cw[2];
    cen[t * 4 + 0] = v2;
    cen[t * 4 + 1] = v1;
    cen[t * 4 + 2] = -v0;
    cen[t * 4 + 3] = 0.0f;
}

// ---------------------------------------------------------------- main kernel
// R6 accumulation scheme (LDS psum + replicated-atomic tail flush, proven
// 274.5us) with LDS shrunk to 29,188 B -> 5 blocks/CU (grid 1200 fully
// resident, NO straggler tail):
//  - pgeo LDS deleted: every thread redundantly computes its own pixel's
//    geometry into registers (one-time, L1-shared reads)
//  - cen_s LDS deleted: centers read per-iter from the 12KB global table
//    (wave-uniform dwordx4 -> one broadcast transaction, L1-hot)
__global__ __launch_bounds__(256, 5) void k_main(
        const float* __restrict__ normal,
        const float* __restrict__ depth,
        const float* __restrict__ envm,
        const float* __restrict__ camK,
        const float* __restrict__ cen,
        float* __restrict__ wsum8,
        float* __restrict__ msum8,
        float* __restrict__ out) {

    __shared__ __align__(16) u32   env01[128 * 32];   // (ch1<<16)|ch0, [texel][pix]
    __shared__               u16   env2 [128 * 32];   // ch2 bf16, [texel][pix]
    __shared__               float psum[NGRIDS * 3];  // block-local acc sums
    __shared__               float pmask;             // block-local mask sum

    const int tid = threadIdx.x;
    const int bid = blockIdx.x;
    const int b   = bid / 600;
    const int pg  = bid % 600;       // 0..599 pixel group (32 px)
    const int p0  = pg * 32;
    const int pix  = tid & 31;
    const int slot = tid >> 5;       // 0..7

    // ---- zero block-local accumulators (visible after the staging barrier)
    for (int i = tid; i < NGRIDS * 3; i += 256) psum[i] = 0.0f;
    if (tid == 0) pmask = 0.0f;

    // ---- stage env tile once (f32 -> packed bf16 LDS). 1024 tasks =
    // 32 pix x 32 texel-quads; lanes = consecutive pixels -> LDS write
    // bank = pix (2-way across wave halves = free).
    #pragma unroll
    for (int k = 0; k < 4; ++k) {
        int ci  = tid + k * 256;          // 0..1023
        int px_ = ci & 31;
        int tq  = ci >> 5;                // 0..31
        size_t base = ((size_t)b * 3 * NPIX + p0 + px_) * 128 + tq * 4;
        const float4 v0 = *reinterpret_cast<const float4*>(&envm[base]);
        const float4 v1 = *reinterpret_cast<const float4*>(&envm[base + (size_t)NPIX * 128]);
        const float4 v2 = *reinterpret_cast<const float4*>(&envm[base + (size_t)2 * NPIX * 128]);
        const float a0[4] = {v0.x, v0.y, v0.z, v0.w};
        const float a1[4] = {v1.x, v1.y, v1.z, v1.w};
        const float a2[4] = {v2.x, v2.y, v2.z, v2.w};
        #pragma unroll
        for (int j = 0; j < 4; ++j) {
            int t = tq * 4 + j;
            env01[t * 32 + px_] = ((u32)f2bf(a1[j]) << 16) | (u32)f2bf(a0[j]);
            env2 [t * 32 + px_] = f2bf(a2[j]);
        }
    }

    // ---- per-pixel geometry: ALL threads compute their own pixel's values
    // into registers (8x redundant, one-time, reads L1-shared within block)
    float ptx, pty, ptz, A0, A1, A2, A3, A4, A5, A6, A7, A8, mask;
    {
        int p = p0 + pix;
        int r = p / ENV_COL, c = p % ENV_COL;
        float nv[3];
        #pragma unroll
        for (int ch = 0; ch < 3; ++ch) {
            const float* np_ = &normal[((size_t)(b * 3 + ch) * IM_H + 2 * r) * IM_W + 2 * c];
            nv[ch] = 0.25f * (np_[0] + np_[1] + np_[IM_W] + np_[IM_W + 1]);
        }
        float s2 = nv[0]*nv[0] + nv[1]*nv[1] + nv[2]*nv[2];
        s2 = fminf(fmaxf(s2, 1e-6f), 1.0f);
        float inv = 1.0f / sqrtf(s2);
        nv[0] *= inv; nv[1] *= inv; nv[2] *= inv;
        // camy = normalize(up - (up.n) n), up=(0,1,0)
        float ty0 = -nv[1]*nv[0], ty1 = 1.0f - nv[1]*nv[1], ty2 = -nv[1]*nv[2];
        float tn = fmaxf(sqrtf(ty0*ty0 + ty1*ty1 + ty2*ty2), 1e-12f);
        float cy0 = ty0/tn, cy1 = ty1/tn, cy2 = ty2/tn;
        // camx = -normalize(cross(camy, n))
        float cr0 = cy1*nv[2] - cy2*nv[1];
        float cr1 = cy2*nv[0] - cy0*nv[2];
        float cr2 = cy0*nv[1] - cy1*nv[0];
        float cnm = fmaxf(sqrtf(cr0*cr0 + cr1*cr1 + cr2*cr2), 1e-12f);
        float cx0 = -cr0/cnm, cx1 = -cr1/cnm, cx2 = -cr2/cnm;
        // A = [camx camy n] columns, + 1e-6 I ; invert (adjugate)
        float a = cx0 + 1e-6f, bb = cy0,         cc = nv[0];
        float d = cx1,         e  = cy1 + 1e-6f, f  = nv[1];
        float g2 = cx2,        h  = cy2,         i  = nv[2] + 1e-6f;
        float c00 = e*i - f*h,   c01 = f*g2 - d*i,  c02 = d*h - e*g2;
        float c10 = cc*h - bb*i, c11 = a*i - cc*g2, c12 = bb*g2 - a*h;
        float c20 = bb*f - cc*e, c21 = cc*d - a*f,  c22 = a*e - bb*d;
        float rdet = 1.0f / (a*c00 + bb*c01 + cc*c02);
        float K00 = camK[b * 9 + 0];
        float K02 = camK[b * 9 + 2];
        float fpix = K00 * (IM_W / 2.0f) / K02;
        float z = -depth[((size_t)b * IM_H + 2 * r) * IM_W + 2 * c];
        ptx = -((2.0f * c) - IM_W / 2.0f) / fpix * z;
        pty =  ((2.0f * r) - IM_H / 2.0f) / fpix * z;
        ptz = z;
        mask = (z < -0.1f) ? 1.0f : 0.0f;
        A0 = c00*rdet; A1 = c10*rdet; A2 = c20*rdet;
        A3 = c01*rdet; A4 = c11*rdet; A5 = c21*rdet;
        A6 = c02*rdet; A7 = c12*rdet; A8 = c22*rdet;
        if (tid < 32) out[MASK_OFF + (size_t)b * NPIX + p] = mask;
    }

    __syncthreads();

    // ---- block mask sum (after barrier so pmask zero-init is visible)
    if (tid < 32) {
        float ms = row16_sum(mask);        // rows 0,1 fully active
        if ((tid & 15) == 0) atomicAdd(&pmask, ms);
    }

    const float mscale = mask * 0.1f;
    const float* const cbase = &cen[(size_t)b * NGRIDS * 4];

    #pragma unroll 4
    for (int it = 0; it < 48; ++it) {
        const int n = it * 8 + slot;                   // 0..383
        // wave-uniform dwordx4 from the L1-hot centers table
        const float4 cc4 = *reinterpret_cast<const float4*>(&cbase[n * 4]);
        const float vx = cc4.x - ptx;
        const float vy = cc4.y - pty;
        const float vz = cc4.z - ptz;
        float lx = A0 * vx + A1 * vy + A2 * vz;
        float ly = A3 * vx + A4 * vy + A5 * vz;
        float lz = A6 * vx + A7 * vy + A8 * vz;
        float rn = __builtin_amdgcn_rsqf(lx * lx + ly * ly + lz * lz);
        float ct = fminf(fmaxf(lz * rn, -1.0f), 1.0f);
        float theta = fast_acos(ct);
        float phi = fast_atan2(ly, lx);                // sin_t>0 divides out
        float az = phi * 2.54647908947032537f + 7.5f;  // phi*(8/pi)+7.5
        float el = theta * 5.09295817894065074f - 0.5f;// theta*(16/pi)-0.5
        float x = fminf(fmaxf(az, 0.0f), 15.0f);
        float y = fminf(fmaxf(el, 0.0f), 7.0f);
        float x0f = floorf(x), y0f = floorf(y);
        float wx = x - x0f, wy = y - y0f;
        int ix0 = (int)x0f, iy0 = (int)y0f;
        int ix1 = min(ix0 + 1, 15), iy1 = min(iy0 + 1, 7);
        int t00 = (iy0 << 4) + ix0;       // texel ids
        int t01 = (iy0 << 4) + ix1;
        int t10 = (iy1 << 4) + ix0;
        int t11 = (iy1 << 4) + ix1;
        u32 c00 = env01[(t00 << 5) + pix], c01 = env01[(t01 << 5) + pix];
        u32 c10 = env01[(t10 << 5) + pix], c11 = env01[(t11 << 5) + pix];
        u32 g00 = env2 [(t00 << 5) + pix], g01 = env2 [(t01 << 5) + pix];
        u32 g10 = env2 [(t10 << 5) + pix], g11 = env2 [(t11 << 5) + pix];
        // fold mask*0.1 into the bilinear weights
        float wy1m = wy * mscale, wy0m = mscale - wy1m;
        float w00 = wy0m * (1.0f - wx), w01 = wy0m * wx;
        float w10 = wy1m * (1.0f - wx), w11 = wy1m * wx;
        float v0 = w00 * __uint_as_float(c00 << 16)
                 + w01 * __uint_as_float(c01 << 16)
                 + w10 * __uint_as_float(c10 << 16)
                 + w11 * __uint_as_float(c11 << 16);
        float v1 = w00 * __uint_as_float(c00 & 0xffff0000u)
                 + w01 * __uint_as_float(c01 & 0xffff0000u)
                 + w10 * __uint_as_float(c10 & 0xffff0000u)
                 + w11 * __uint_as_float(c11 & 0xffff0000u);
        float v2 = w00 * __uint_as_float(g00 << 16)
                 + w01 * __uint_as_float(g01 << 16)
                 + w10 * __uint_as_float(g10 << 16)
                 + w11 * __uint_as_float(g11 << 16);

        size_t obase = ((size_t)b * 3 * NGRIDS + n) * NPIX + p0 + pix;
        out[obase]                             = v0;
        out[obase + (size_t)NGRIDS * NPIX]     = v1;
        out[obase + (size_t)2 * NGRIDS * NPIX] = v2;

        // pure-VALU DPP row sums -> block-local LDS accumulation
        float s0 = row16_sum(v0);
        float s1 = row16_sum(v1);
        float s2v = row16_sum(v2);
        if ((pix & 15) == 0) {
            atomicAdd(&psum[n * 3 + 0], s0);
            atomicAdd(&psum[n * 3 + 1], s1);
            atomicAdd(&psum[n * 3 + 2], s2v);
        }
    }

    // ---- tail flush: block-local sums -> 8-way replicated global accumulators
    __syncthreads();
    {
        float* wrep = &wsum8[((size_t)b * NREP + (bid & (NREP - 1))) * (NGRIDS * 3)];
        for (int i = tid; i < NGRIDS * 3; i += 256)
            atomicAdd(&wrep[i], psum[i]);
        if (tid == 0)
            atomicAdd(&msum8[b * NREP + (bid & (NREP - 1))], pmask);
    }
}

// ------------------------------------------------------------- finalize mean
// 2304 outputs: sum the 8 replicas, divide by masksum.
__global__ __launch_bounds__(256) void k_final(const float* __restrict__ wsum8,
                                               const float* __restrict__ msum8,
                                               float* __restrict__ out) {
    int t = blockIdx.x * 256 + threadIdx.x;
    if (t >= BATCH * NGRIDS * 3) return;
    int b = t / (NGRIDS * 3);
    int i = t % (NGRIDS * 3);
    float ms = 0.0f;
    #pragma unroll
    for (int r = 0; r < NREP; ++r) ms += msum8[b * NREP + r];
    float s = 0.0f;
    #pragma unroll
    for (int r = 0; r < NREP; ++r)
        s += wsum8[((size_t)b * NREP + r) * (NGRIDS * 3) + i];
    // wsum layout [n][ch] == mean layout (B, NGRIDS, 3): straight index
    out[MEAN_OFF + t] = s / (ms + 1e-6f);
}

extern "C" void kernel_launch(void* const* d_in, const int* in_sizes, int n_in,
                              void* d_out, int out_size, void* d_ws, size_t ws_size,
                              hipStream_t stream) {
    const float* normal = (const float*)d_in[0];
    const float* depth  = (const float*)d_in[1];
    const float* envm   = (const float*)d_in[2];
    const float* camK   = (const float*)d_in[3];
    const float* camR   = (const float*)d_in[4];
    const float* layout = (const float*)d_in[5];
    float* out = (float*)d_out;
    float* ws  = (float*)d_ws;

    hipMemsetAsync(ws, 0, WS_ZERO_F * sizeof(float), stream);
    k_centers<<<dim3(3), dim3(256), 0, stream>>>(layout, camR, ws + WS_CEN);
    k_main<<<dim3(BATCH * 600), dim3(256), 0, stream>>>(normal, depth, envm, camK,
                                                        ws + WS_CEN,
                                                        ws + WS_SUM8, ws + WS_MSUM8,
                                                        out);
    k_final<<<dim3(9), dim3(256), 0, stream>>>(ws + WS_SUM8, ws + WS_MSUM8, out);
}